// Round 4
// baseline (199.700 us; speedup 1.0000x reference)
//
#include <hip/hip_runtime.h>

#define DIM 256

typedef float f32x4 __attribute__((ext_vector_type(4)));  // native vector: OK for nontemporal builtin

// One wave = 128 contiguous rows (one 128 KiB contiguous output chunk).
// Both x-loads (64 rows each) issue up front for MLP; each row's timestep is
// broadcast in-register via __shfl (v_readlane at constant index). Lane j
// writes dims [4j,4j+4) of each row: one float4 = 1 KiB contiguous per wave
// per row. Stores are NON-TEMPORAL (nt): the 1 GiB stream has zero reuse, so
// bypass L2 write-allocate instead of churning 32 MiB of dirty lines.
// v_sin/v_cos take REVOLUTIONS: premultiply freqs by 1/(2pi), fract-reduce.
__global__ __launch_bounds__(256) void SinusoidalEmbedding_kernel(
    const float* __restrict__ x, float* __restrict__ out, int n) {
    const int lane = threadIdx.x & 63;
    const int wid = blockIdx.x * (blockDim.x >> 6) + (threadIdx.x >> 6);
    const int nw = gridDim.x * (blockDim.x >> 6);
    const int ROWS = 128;

    const float k = 0.103810252965228506f;      // log2(10000)/128
    const float INV2PI = 0.15915494309189535f;  // radians -> revolutions
    const float i0 = (float)(2 * lane);
    const float g0 = exp2f(-i0 * k) * INV2PI;          // lane's freq 2j
    const float g1 = exp2f(-(i0 + 1.0f) * k) * INV2PI; // lane's freq 2j+1

    for (int base = wid * ROWS; base < n; base += nw * ROWS) {
        // Issue both 64-row timestep loads immediately (independent, MLP).
        const int r0 = base + lane;
        const int r1 = base + 64 + lane;
        const float xv0 = (r0 < n) ? x[r0] : 0.0f;
        const float xv1 = (r1 < n) ? x[r1] : 0.0f;
        float* o = out + (size_t)base * DIM + lane * 4;
        const int nb = min(ROWS, n - base);

        if (nb == ROWS) {
            #pragma unroll 8
            for (int r = 0; r < 64; ++r) {
                const float xr = __shfl(xv0, r);
                float t0 = xr * g0; t0 -= floorf(t0);  // v_fract
                float t1 = xr * g1; t1 -= floorf(t1);
                f32x4 v;
                v.x = __builtin_amdgcn_sinf(t0);  // sin(2*pi*t)
                v.y = __builtin_amdgcn_cosf(t0);
                v.z = __builtin_amdgcn_sinf(t1);
                v.w = __builtin_amdgcn_cosf(t1);
                __builtin_nontemporal_store(v, reinterpret_cast<f32x4*>(o + (size_t)r * DIM));
            }
            #pragma unroll 8
            for (int r = 0; r < 64; ++r) {
                const float xr = __shfl(xv1, r);
                float t0 = xr * g0; t0 -= floorf(t0);
                float t1 = xr * g1; t1 -= floorf(t1);
                f32x4 v;
                v.x = __builtin_amdgcn_sinf(t0);
                v.y = __builtin_amdgcn_cosf(t0);
                v.z = __builtin_amdgcn_sinf(t1);
                v.w = __builtin_amdgcn_cosf(t1);
                __builtin_nontemporal_store(v, reinterpret_cast<f32x4*>(o + (size_t)(64 + r) * DIM));
            }
        } else {
            for (int r = 0; r < nb; ++r) {  // tail — not hit at n=1048576
                const float xr = (r < 64) ? __shfl(xv0, r & 63) : __shfl(xv1, r & 63);
                float t0 = xr * g0; t0 -= floorf(t0);
                float t1 = xr * g1; t1 -= floorf(t1);
                f32x4 v;
                v.x = __builtin_amdgcn_sinf(t0);
                v.y = __builtin_amdgcn_cosf(t0);
                v.z = __builtin_amdgcn_sinf(t1);
                v.w = __builtin_amdgcn_cosf(t1);
                __builtin_nontemporal_store(v, reinterpret_cast<f32x4*>(o + (size_t)r * DIM));
            }
        }
    }
}

extern "C" void kernel_launch(void* const* d_in, const int* in_sizes, int n_in,
                              void* d_out, int out_size, void* d_ws, size_t ws_size,
                              hipStream_t stream) {
    const float* x = (const float*)d_in[0];
    float* out = (float*)d_out;
    const int n = in_sizes[0];  // 1048576 rows

    const int block = 256;  // 4 waves/block
    const int grid = 2048;  // 8192 waves -> exactly 1 batch of 128 rows each
    SinusoidalEmbedding_kernel<<<grid, block, 0, stream>>>(x, out, n);
}